// Round 14
// baseline (2402.627 us; speedup 1.0000x reference)
//
#include <hip/hip_runtime.h>
#include <hip/hip_bf16.h>
#include <math.h>

// ---------------------------------------------------------------------------
// Problem constants
// ---------------------------------------------------------------------------
#define BB 32
#define SS 60
#define NN_ 25
#define DIN 100
#define BN 800           // B*N
#define GRU_H 512
#define FDIM 1024        // TEMB+SEMB
#define CH 256
#define OUTD 512

typedef unsigned short ushort_t;
typedef unsigned int u32;
typedef unsigned long long u64;
typedef float f32x4 __attribute__((ext_vector_type(4)));
typedef __bf16 bf16x8 __attribute__((ext_vector_type(8)));
typedef short s16x8 __attribute__((ext_vector_type(8)));

// workspace float offsets
static const size_t O_HSEQB = 0;          // bf16 48000*512 = 12,288,000 fl
static const size_t O_WB    = 12288000;   // bf16 GRU weights, 1,572,864 fl
static const size_t O_HF32  = 13860864;   // fp32 [dir][800*512] final hidden
static const size_t O_HRING = 14680064;   // bf16 ring3 [slot][dir][800*512]
static const size_t O_HN    = 15908864;
static const size_t O_QKV   = 16728064;
static const size_t O_SC    = 18366464;
static const size_t O_ADJ   = 18530304;
static const size_t O_WR    = 18530944;
static const size_t O_TEP   = 18940544;
static const size_t O_TE    = 18953344;
static const size_t O_XCAT  = 18966144;
static const size_t O_GTMP  = 19990144;
static const size_t O_XG0   = 20194944;
static const size_t O_XG1   = 20399744;
static const size_t O_XG2   = 20604544;
// bf16 weight buffers (pre-transposed to [N][K])
static const size_t O_W1TB  = 20809344;   // 256x128
static const size_t O_W2TB  = 20825728;   // 512x256
static const size_t O_AWB   = 20891264;   // 2048x1024
static const size_t O_FTWB  = 21939840;   // 512x1024
static const size_t O_SMWB  = 22201984;   // 512x768
static const size_t O_G0WB  = 22398592;   // 256x1024
static const size_t O_G1WB  = 22529664;   // 256x256
static const size_t O_G2WB  = 22562432;   // 256x256
static const size_t O_FCWB  = 22595200;   // 512x1280
static const size_t O_FLAGS = 22922880;   // 26 chain flags (16-int stride) + 8 XCD queue counters @ +448

__device__ __forceinline__ ushort_t f2b(float v)
{
  __hip_bfloat16 b = __float2bfloat16(v);
  return *reinterpret_cast<ushort_t*>(&b);
}

__device__ __forceinline__ float sig_fast(float v)
{
  return 1.f / (1.f + __expf(-v));
}
__device__ __forceinline__ float tanh_fast(float v)
{
  return 1.f - 2.f / (1.f + __expf(2.f * v));
}

__device__ __forceinline__ void block_reduce2(float& s, float& q, float* scratch)
{
  __syncthreads();
  #pragma unroll
  for (int off = 32; off > 0; off >>= 1) {
    s += __shfl_down(s, off);
    q += __shfl_down(q, off);
  }
  int tid = threadIdx.x;
  int w = tid >> 6;
  if ((tid & 63) == 0) { scratch[w * 2] = s; scratch[w * 2 + 1] = q; }
  __syncthreads();
  if (tid == 0) {
    float ss = 0.f, qq = 0.f;
    int nw = blockDim.x >> 6;
    for (int i = 0; i < nw; i++) { ss += scratch[i * 2]; qq += scratch[i * 2 + 1]; }
    scratch[0] = ss; scratch[1] = qq;
  }
  __syncthreads();
  s = scratch[0]; q = scratch[1];
}

// ---------------------------------------------------------------------------
// merged conversions
// ---------------------------------------------------------------------------
__global__ __launch_bounds__(256) void k_cvt_plain_all(
    const float* __restrict__ wih_f, const float* __restrict__ whh_f,
    const float* __restrict__ wih_b, const float* __restrict__ whh_b,
    const float* __restrict__ attn_w,
    ushort_t* __restrict__ wb, ushort_t* __restrict__ awb)
{
  int i = blockIdx.x * 256 + threadIdx.x;   // 0..786431
  wb[i]           = f2b(wih_f[i]);
  wb[786432 + i]  = f2b(whh_f[i]);
  wb[1572864 + i] = f2b(wih_b[i]);
  wb[2359296 + i] = f2b(whh_b[i]);
  awb[i]          = f2b(attn_w[i]);
  awb[786432 + i] = f2b(attn_w[786432 + i]);
  int j = 1572864 + i;
  if (j < 2097152) awb[j] = f2b(attn_w[j]);
}

struct TJob {
  const float* src; ushort_t* dst;
  int K, N, KP, base;
};

// transpose [K][N] fp32 -> [N][KP] bf16, 8 jobs, one launch
__global__ __launch_bounds__(256) void k_cvt_t_all(
    TJob j0, TJob j1, TJob j2, TJob j3, TJob j4, TJob j5, TJob j6, TJob j7)
{
  __shared__ float tile[32][33];
  int t = blockIdx.x;
  TJob jb = j0;
  if (t >= j7.base) jb = j7;
  else if (t >= j6.base) jb = j6;
  else if (t >= j5.base) jb = j5;
  else if (t >= j4.base) jb = j4;
  else if (t >= j3.base) jb = j3;
  else if (t >= j2.base) jb = j2;
  else if (t >= j1.base) jb = j1;
  int local = t - jb.base;
  int ktiles = (jb.KP + 31) >> 5;
  int n0 = (local / ktiles) * 32;
  int k0 = (local % ktiles) * 32;
  int tx = threadIdx.x & 31, ty = threadIdx.x >> 5;
  #pragma unroll
  for (int i = 0; i < 4; i++) {
    int k = k0 + ty + i * 8, n = n0 + tx;
    tile[ty + i * 8][tx] = (k < jb.K && n < jb.N) ? jb.src[(size_t)k * jb.N + n] : 0.f;
  }
  __syncthreads();
  #pragma unroll
  for (int i = 0; i < 4; i++) {
    int n = n0 + ty + i * 8, k = k0 + tx;
    if (n < jb.N && k < jb.KP) jb.dst[(size_t)n * jb.KP + k] = f2b(tile[tx][ty + i * 8]);
  }
}

// ---------------------------------------------------------------------------
// K1: fused MLP (100->256 relu -> 512 relu) + LN(512), all-MFMA, bf16 out.
// ---------------------------------------------------------------------------
__global__ __launch_bounds__(256, 1) void k_mlp_fused(
    const float* __restrict__ x,
    const ushort_t* __restrict__ w1tb,   // [256][128]
    const float* __restrict__ b1,
    const ushort_t* __restrict__ w2tb,   // [512][256]
    const float* __restrict__ b2,
    const float* __restrict__ g, const float* __restrict__ be,
    ushort_t* __restrict__ hseqb)
{
  __shared__ __align__(16) ushort_t xb[64][136];
  __shared__ __align__(16) ushort_t Bl[512][40];
  __shared__ __align__(16) ushort_t h1[64][264];
  const int tid = threadIdx.x;
  const int r0 = blockIdx.x * 64;

  {
    int rr = tid >> 2;
    int d0 = (tid & 3) * 32;
    int r = r0 + rr;
    int bn = r / SS, s = r % SS;
    int b = bn / NN_, n = bn % NN_;
    const float* xp = x + (((size_t)b * SS + s) * NN_ + n) * DIN;
    ushort_t tmp[32];
    #pragma unroll
    for (int i = 0; i < 32; i++) {
      int d = d0 + i;
      tmp[i] = (d < DIN) ? f2b(xp[d]) : (ushort_t)0;
    }
    #pragma unroll
    for (int i = 0; i < 4; i++)
      *reinterpret_cast<s16x8*>(&xb[rr][d0 + i * 8]) = *reinterpret_cast<s16x8*>(&tmp[i * 8]);
  }
  const int wid = tid >> 6, l = tid & 63, lr = l & 15, lg = l >> 4;
  const int srow = tid >> 2, skg = (tid & 3) * 8;

  // ---- layer 1: 64x256, K=128 ----
  f32x4 acc1[16] = {};
  for (int kc = 0; kc < 4; kc++) {
    __syncthreads();
    #pragma unroll
    for (int i = 0; i < 4; i++) {
      int row = srow + i * 64;
      *reinterpret_cast<s16x8*>(&Bl[row][skg]) =
          *reinterpret_cast<const s16x8*>(w1tb + (size_t)row * 128 + kc * 32 + skg);
    }
    __syncthreads();
    bf16x8 aF = *reinterpret_cast<const bf16x8*>(&xb[wid * 16 + lr][kc * 32 + lg * 8]);
    #pragma unroll
    for (int ni = 0; ni < 16; ni++) {
      bf16x8 bF = *reinterpret_cast<const bf16x8*>(&Bl[ni * 16 + lr][lg * 8]);
      acc1[ni] = __builtin_amdgcn_mfma_f32_16x16x32_bf16(aF, bF, acc1[ni], 0, 0, 0);
    }
  }
  #pragma unroll
  for (int ni = 0; ni < 16; ni++) {
    #pragma unroll
    for (int r = 0; r < 4; r++) {
      int row = wid * 16 + lg * 4 + r;
      int col = ni * 16 + lr;
      h1[row][col] = f2b(fmaxf(acc1[ni][r] + b1[col], 0.f));
    }
  }

  // ---- layer 2: 64x512, K=256 ----
  f32x4 acc2[32] = {};
  for (int kc = 0; kc < 8; kc++) {
    __syncthreads();
    #pragma unroll
    for (int i = 0; i < 8; i++) {
      int row = srow + i * 64;
      *reinterpret_cast<s16x8*>(&Bl[row][skg]) =
          *reinterpret_cast<const s16x8*>(w2tb + (size_t)row * 256 + kc * 32 + skg);
    }
    __syncthreads();
    bf16x8 aF = *reinterpret_cast<const bf16x8*>(&h1[wid * 16 + lr][kc * 32 + lg * 8]);
    #pragma unroll
    for (int ni = 0; ni < 32; ni++) {
      bf16x8 bF = *reinterpret_cast<const bf16x8*>(&Bl[ni * 16 + lr][lg * 8]);
      acc2[ni] = __builtin_amdgcn_mfma_f32_16x16x32_bf16(aF, bF, acc2[ni], 0, 0, 0);
    }
  }

  // ---- bias + relu + in-register LN over 512 ----
  float su[4] = {0.f, 0.f, 0.f, 0.f}, sq[4] = {0.f, 0.f, 0.f, 0.f};
  #pragma unroll
  for (int ni = 0; ni < 32; ni++) {
    float bb = b2[ni * 16 + lr];
    #pragma unroll
    for (int r = 0; r < 4; r++) {
      float v = fmaxf(acc2[ni][r] + bb, 0.f);
      acc2[ni][r] = v;
      su[r] += v; sq[r] += v * v;
    }
  }
  #pragma unroll
  for (int off = 1; off < 16; off <<= 1) {
    #pragma unroll
    for (int r = 0; r < 4; r++) {
      su[r] += __shfl_xor(su[r], off);
      sq[r] += __shfl_xor(sq[r], off);
    }
  }
  #pragma unroll
  for (int r = 0; r < 4; r++) {
    float mean = su[r] * (1.f / 512.f);
    float var = sq[r] * (1.f / 512.f) - mean * mean;
    float rs = rsqrtf(var + 1e-5f);
    int rowg = r0 + wid * 16 + lg * 4 + r;
    ushort_t* outp = hseqb + (size_t)rowg * 512;
    #pragma unroll
    for (int ni = 0; ni < 32; ni++) {
      int col = ni * 16 + lr;
      outp[col] = f2b((acc2[ni][r] - mean) * rs * g[col] + be[col]);
    }
  }
}

// ---------------------------------------------------------------------------
// K2: PERSISTENT GRU, 60 steps, one launch. v4:
//   - items split to 64m x 32j (416 items); grid 512 -> 2 working blocks/CU
//     (2 waves/SIMD TLP, the missing latency hiding).
//   - weights + x: per-lane global fragments (L2/L3), no LDS round-trip.
//   - h: staged full-K in LDS once/step (1x multiplicity, L2-local).
//   - chain flags: WORKGROUP-scope atomic add (executes at local XCD L2)
//     + volatile poll -> no IC round trip. Sound because XCC_ID work-claim
//     guarantees all 16 writers of a chain share one XCD/L2.
//   - ring-3 h buffer; skew <= 1 step.
// ---------------------------------------------------------------------------
__global__ __launch_bounds__(256, 2) void k_gru_persist(
    const ushort_t* __restrict__ hseqb, const ushort_t* __restrict__ wb,
    const float* __restrict__ bih_f, const float* __restrict__ bhh_f,
    const float* __restrict__ bih_b, const float* __restrict__ bhh_b,
    float* __restrict__ hf32, ushort_t* __restrict__ hring,
    int* __restrict__ flags)
{
  __shared__ __align__(16) ushort_t Hf[64][520];   // 66.6 KB full-K h
  __shared__ __align__(16) ushort_t hpack[64][36]; // 4.6 KB pack buffer
  __shared__ int s_item;

  const int tid = threadIdx.x;

  // ---- XCD-local work claim ----
  int* qcnt = flags + 448;   // 8 counters
  if (tid == 0) {
    u32 xcc;
    asm volatile("s_getreg_b32 %0, hwreg(HW_REG_XCC_ID)" : "=s"(xcc));
    xcc &= 7u;
    int idx = __hip_atomic_fetch_add(qcnt + xcc, 1, __ATOMIC_RELAXED,
                                     __HIP_MEMORY_SCOPE_AGENT);
    s_item = (idx << 3) | (int)xcc;
  }
  __syncthreads();
  const int xcd = s_item & 7;
  const int idx = s_item >> 3;
  if (idx >= 64) return;
  const int x3 = xcd & 3;
  const int dir = xcd >> 2;
  const int jt = idx & 15;                // 0..15 (32-wide j tiles)
  const int mt = (idx >> 4) * 4 + x3;     // {x3, x3+4, x3+8, x3+12}
  if (mt >= 13) return;
  const int j0g = jt * 32;
  const int m0g = mt * 64;
  const int chain = dir * 13 + mt;        // 26 chains x 16 writer blocks
  int* flagp = flags + chain * 16;

  const ushort_t* __restrict__ wih = wb + (size_t)dir * 1572864;
  const ushort_t* __restrict__ whh = wih + 786432;
  const float* __restrict__ bih = dir ? bih_b : bih_f;
  const float* __restrict__ bhh = dir ? bhh_b : bhh_f;
  const size_t dirOff = (size_t)dir * 409600;

  const int srow = tid >> 2;          // staging row 0..63
  const int skg  = (tid & 3) * 8;     // staging k offset (x8 ushort)
  const int smg  = m0g + srow;
  const int smg_c = (smg < BN) ? smg : 0;

  // wave layout: wave = 32m x 16j. wm = wid>>1 (m half), wj = wid&1 (j half)
  const int wid = tid >> 6;
  const int l = tid & 63;
  const int lr = l & 15;
  const int lg = l >> 4;
  const int mbase = (wid >> 1) * 32;
  const int jg = j0g + (wid & 1) * 16 + lr;   // this thread's output column j

  // per-gate weight fragment pointers (per-lane, constant across steps)
  const ushort_t* pwf[6];
  #pragma unroll
  for (int tt = 0; tt < 6; tt++) {
    const ushort_t* src = (tt < 3) ? wih : whh;
    int gate = (tt < 3) ? tt : tt - 3;
    pwf[tt] = src + ((size_t)(gate * 512 + jg) * 512) + lg * 8;
  }

  // x fragment rows (per mi, clamped)
  int xrow[2];
  #pragma unroll
  for (int mi = 0; mi < 2; mi++) {
    int m = m0g + mbase + mi * 16 + lr;
    xrow[mi] = (m < BN) ? m : (BN - 1);
  }

  // hoisted per-column biases (j fixed per thread)
  const float rbr  = bih[jg] + bhh[jg];
  const float rbz  = bih[512 + jg] + bhh[512 + jg];
  const float rbin = bih[1024 + jg];
  const float rbhn = bhh[1024 + jg];

  // h carried in registers (block owns the same 64x32 slice every step)
  float hpreg[2][4] = {};   // [mi][r]

  for (int t = 0; t < SS; ++t) {
    const int xt = dir ? (SS - 1 - t) : t;
    const ushort_t* __restrict__ hprev = hring + (size_t)(t % 3) * 819200 + dirOff;
    ushort_t* __restrict__ hnew = hring + (size_t)((t + 1) % 3) * 819200 + dirOff;

    // per-step x fragment base pointers
    const ushort_t* pxf[2];
    #pragma unroll
    for (int mi = 0; mi < 2; mi++)
      pxf[mi] = hseqb + ((size_t)xrow[mi] * SS + xt) * 512 + lg * 8;

    // ---- chain-flag wait (volatile load -> local XCD L2) ----
    if (t > 0 && tid == 0) {
      while (*(volatile const int*)flagp < 16 * t) {
        __builtin_amdgcn_s_sleep(2);
      }
    }
    __syncthreads();   // (A) flag seen by all; previous-step LDS readers done

    // ---- stage h (volatile sc0, local-XCD L2) into full-K LDS ----
    {
      const ushort_t* ph = hprev + (size_t)smg_c * 512 + skg;
      u64 hv[32];
      #pragma unroll
      for (int c = 0; c < 16; c++) {
        hv[2 * c]     = *reinterpret_cast<const volatile u64*>(ph + c * 32);
        hv[2 * c + 1] = *reinterpret_cast<const volatile u64*>(ph + c * 32 + 4);
      }
      #pragma unroll
      for (int c = 0; c < 16; c++) {
        *reinterpret_cast<u64*>(&Hf[srow][c * 32 + skg])     = hv[2 * c];
        *reinterpret_cast<u64*>(&Hf[srow][c * 32 + skg + 4]) = hv[2 * c + 1];
      }
    }
    __syncthreads();   // (B) Hf ready; read-only below -> no inner barriers

    f32x4 accr[2] = {};
    f32x4 accz[2] = {};
    f32x4 accin[2] = {};
    f32x4 acchn[2] = {};

    #pragma unroll 4
    for (int it = 0; it < 16; ++it) {
      const int k0 = it * 32;
      bf16x8 bW[6];
      #pragma unroll
      for (int tt = 0; tt < 6; tt++)
        bW[tt] = *reinterpret_cast<const bf16x8*>(pwf[tt] + k0);
      bf16x8 xA[2], hA[2];
      #pragma unroll
      for (int mi = 0; mi < 2; mi++) {
        xA[mi] = *reinterpret_cast<const bf16x8*>(pxf[mi] + k0);
        hA[mi] = *reinterpret_cast<const bf16x8*>(&Hf[mbase + mi * 16 + lr][k0 + lg * 8]);
      }
      #pragma unroll
      for (int mi = 0; mi < 2; mi++) {
        accr[mi]  = __builtin_amdgcn_mfma_f32_16x16x32_bf16(xA[mi], bW[0], accr[mi], 0, 0, 0);
        accr[mi]  = __builtin_amdgcn_mfma_f32_16x16x32_bf16(hA[mi], bW[3], accr[mi], 0, 0, 0);
        accz[mi]  = __builtin_amdgcn_mfma_f32_16x16x32_bf16(xA[mi], bW[1], accz[mi], 0, 0, 0);
        accz[mi]  = __builtin_amdgcn_mfma_f32_16x16x32_bf16(hA[mi], bW[4], accz[mi], 0, 0, 0);
        accin[mi] = __builtin_amdgcn_mfma_f32_16x16x32_bf16(xA[mi], bW[2], accin[mi], 0, 0, 0);
        acchn[mi] = __builtin_amdgcn_mfma_f32_16x16x32_bf16(hA[mi], bW[5], acchn[mi], 0, 0, 0);
      }
    }

    // ---- gate epilogue: update register-resident h ----
    #pragma unroll
    for (int mi = 0; mi < 2; mi++) {
      #pragma unroll
      for (int r = 0; r < 4; r++) {
        float sr = accr[mi][r] + rbr;
        float sz = accz[mi][r] + rbz;
        float rg = sig_fast(sr);
        float zg = sig_fast(sz);
        float ng = tanh_fast(accin[mi][r] + rbin + rg * (acchn[mi][r] + rbhn));
        hpreg[mi][r] = (1.f - zg) * ng + zg * hpreg[mi][r];
      }
    }

    if (t < SS - 1) {
      // pack h_new bf16, coalesced 16B stores to local L2
      #pragma unroll
      for (int mi = 0; mi < 2; mi++)
        #pragma unroll
        for (int r = 0; r < 4; r++)
          hpack[mbase + mi * 16 + lg * 4 + r][(wid & 1) * 16 + lr] = f2b(hpreg[mi][r]);
      __syncthreads();   // (D)
      {
        int row = tid >> 2;
        int gm = m0g + row;
        if (gm < BN) {
          ushort_t* dst = hnew + (size_t)gm * 512 + j0g + (tid & 3) * 8;
          *reinterpret_cast<s16x8*>(dst) =
              *reinterpret_cast<s16x8*>(&hpack[row][(tid & 3) * 8]);
        }
      }
      __syncthreads();   // (E) drains vmcnt(0): stores in L2 before flag add
      if (tid == 0)
        __hip_atomic_fetch_add(flagp, 1, __ATOMIC_RELAXED, __HIP_MEMORY_SCOPE_WORKGROUP);
    } else {
      // final step: write fp32 hidden for k_ln_hn
      float* hfin = hf32 + dirOff;
      #pragma unroll
      for (int mi = 0; mi < 2; mi++) {
        #pragma unroll
        for (int r = 0; r < 4; r++) {
          int m = m0g + mbase + mi * 16 + lg * 4 + r;
          if (m < BN) hfin[(size_t)m * 512 + jg] = hpreg[mi][r];
        }
      }
    }
  }
}

// ---------------------------------------------------------------------------
// K3: hn = LN(concat(hf, hb)) over 1024.
// ---------------------------------------------------------------------------
__global__ __launch_bounds__(256) void k_ln_hn(
    const float* __restrict__ hf, const float* __restrict__ hb,
    const float* __restrict__ g, const float* __restrict__ be,
    float* __restrict__ hn)
{
  __shared__ float scratch[8];
  int row = blockIdx.x, tid = threadIdx.x;
  float v[4];
  float s = 0.f, q = 0.f;
  #pragma unroll
  for (int p = 0; p < 4; p++) {
    int c = p * 256 + tid;
    float val = (c < 512) ? hf[(size_t)row * 512 + c] : hb[(size_t)row * 512 + (c - 512)];
    v[p] = val; s += val; q += val * val;
  }
  block_reduce2(s, q, scratch);
  float mean = s * (1.f / 1024.f);
  float var = q * (1.f / 1024.f) - mean * mean;
  float rs = rsqrtf(var + 1e-5f);
  #pragma unroll
  for (int p = 0; p < 4; p++) {
    int c = p * 256 + tid;
    hn[(size_t)row * 1024 + c] = (v[p] - mean) * rs * g[c] + be[c];
  }
}

// ---------------------------------------------------------------------------
// bf16 MFMA GEMM: C = act(bias + A(fp32,cvt) @ B(bf16,[N][K])^T)
// ---------------------------------------------------------------------------
template<int ACT>
__global__ __launch_bounds__(256) void k_bgemm(
    const float* __restrict__ A, const ushort_t* __restrict__ B,
    const float* __restrict__ bias, float* __restrict__ C,
    int M, int N, int K, int lda, int ldc)
{
  __shared__ __align__(16) ushort_t Al[64][40];
  __shared__ __align__(16) ushort_t Bl[64][40];
  const int tid = threadIdx.x;
  const int n0g = blockIdx.x * 64, m0g = blockIdx.y * 64;
  const int srow = tid >> 2, skg = (tid & 3) * 8;
  const int smg = (m0g + srow < M) ? (m0g + srow) : (M - 1);
  const int sng = (n0g + srow < N) ? (n0g + srow) : (N - 1);
  const float* pa = A + (size_t)smg * lda + skg;
  const ushort_t* pb = B + (size_t)sng * K + skg;
  const int wid = tid >> 6, l = tid & 63, lr = l & 15, lg = l >> 4;
  const int mbase = (wid >> 1) * 32, nbase = (wid & 1) * 32;
  f32x4 acc[2][2] = {};

  for (int k0 = 0; k0 < K; k0 += 32) {
    float4 a0 = *reinterpret_cast<const float4*>(pa + k0);
    float4 a1 = *reinterpret_cast<const float4*>(pa + k0 + 4);
    s16x8 bv = *reinterpret_cast<const s16x8*>(pb + k0);
    ushort_t tmp[8] = {f2b(a0.x), f2b(a0.y), f2b(a0.z), f2b(a0.w),
                       f2b(a1.x), f2b(a1.y), f2b(a1.z), f2b(a1.w)};
    *reinterpret_cast<s16x8*>(&Al[srow][skg]) = *reinterpret_cast<s16x8*>(tmp);
    *reinterpret_cast<s16x8*>(&Bl[srow][skg]) = bv;
    __syncthreads();
    bf16x8 aF[2], bF[2];
    #pragma unroll
    for (int mi = 0; mi < 2; mi++)
      aF[mi] = *reinterpret_cast<const bf16x8*>(&Al[mbase + mi * 16 + lr][lg * 8]);
    #pragma unroll
    for (int ni = 0; ni < 2; ni++)
      bF[ni] = *reinterpret_cast<const bf16x8*>(&Bl[nbase + ni * 16 + lr][lg * 8]);
    #pragma unroll
    for (int mi = 0; mi < 2; mi++)
      #pragma unroll
      for (int ni = 0; ni < 2; ni++)
        acc[mi][ni] = __builtin_amdgcn_mfma_f32_16x16x32_bf16(aF[mi], bF[ni], acc[mi][ni], 0, 0, 0);
    __syncthreads();
  }
  #pragma unroll
  for (int mi = 0; mi < 2; mi++) {
    #pragma unroll
    for (int r = 0; r < 4; r++) {
      int mg = m0g + mbase + mi * 16 + lg * 4 + r;
      if (mg >= M) continue;
      #pragma unroll
      for (int ni = 0; ni < 2; ni++) {
        int ng = n0g + nbase + ni * 16 + lr;
        if (ng >= N) continue;
        float v = acc[mi][ni][r] + (bias ? bias[ng] : 0.f);
        if (ACT == 1) v = fmaxf(v, 0.f);
        C[(size_t)mg * ldc + ng] = v;
      }
    }
  }
}

// ---------------------------------------------------------------------------
// K4: per (b,h) attention scores + softmax.
// ---------------------------------------------------------------------------
__global__ __launch_bounds__(256) void k_scores(const float* __restrict__ qkv,
                                                float* __restrict__ sc)
{
  int b = blockIdx.x, h = blockIdx.y;
  __shared__ float qs[25][128];
  __shared__ float ks[25][129];
  __shared__ float ps[25][26];
  int tid = threadIdx.x;
  for (int idx = tid; idx < 3200; idx += 256) {
    int i = idx >> 7, d = idx & 127;
    const float* base = qkv + (size_t)(b * 25 + i) * 2048 + h * 128 + d;
    qs[i][d] = base[0];
    ks[i][d] = base[1024];
  }
  __syncthreads();
  const float scale = 0.08838834764831845f;
  for (int e = tid; e < 625; e += 256) {
    int i = e / 25, j = e % 25;
    float s = 0.f;
    for (int d = 0; d < 128; d++) s += qs[i][d] * ks[j][d];
    ps[i][j] = s * scale;
  }
  __syncthreads();
  if (tid < 25) {
    float mx = -1e30f;
    for (int j = 0; j < 25; j++) mx = fmaxf(mx, ps[tid][j]);
    float s = 0.f;
    for (int j = 0; j < 25; j++) { float ev = expf(ps[tid][j] - mx); ps[tid][j] = ev; s += ev; }
    float inv = 1.f / s;
    for (int j = 0; j < 25; j++) ps[tid][j] *= inv;
  }
  __syncthreads();
  float* out = sc + (size_t)(b * 8 + h) * 640;
  for (int e = tid; e < 625; e += 256) out[e] = ps[e / 25][e % 25];
}

// ---------------------------------------------------------------------------
// K5: generic per-row LayerNorm (fp32 src/dst).
// ---------------------------------------------------------------------------
template<int PER>
__global__ __launch_bounds__(256) void k_ln_rows(
    const float* __restrict__ src, float* __restrict__ dst,
    const float* __restrict__ g, const float* __restrict__ be,
    int dstStride, int dstOff)
{
  __shared__ float scratch[8];
  int row = blockIdx.x, tid = threadIdx.x;
  const int C = PER * 256;
  float v[PER];
  float s = 0.f, q = 0.f;
  #pragma unroll
  for (int p = 0; p < PER; p++) {
    v[p] = src[(size_t)row * C + p * 256 + tid];
    s += v[p]; q += v[p] * v[p];
  }
  block_reduce2(s, q, scratch);
  float mean = s / (float)C;
  float var = q / (float)C - mean * mean;
  float rs = rsqrtf(var + 1e-5f);
  #pragma unroll
  for (int p = 0; p < PER; p++) {
    int c = p * 256 + tid;
    dst[(size_t)row * dstStride + dstOff + c] = (v[p] - mean) * rs * g[c] + be[c];
  }
}

__global__ __launch_bounds__(256) void k_bcast_te(const float* __restrict__ te,
                                                  float* __restrict__ xcat)
{
  int row = blockIdx.x, tid = threadIdx.x;
  int n = row % 25;
  xcat[(size_t)row * 1280 + 512 + tid] = te[n * 512 + tid];
  xcat[(size_t)row * 1280 + 768 + tid] = te[n * 512 + 256 + tid];
}

// ---------------------------------------------------------------------------
// K6: adjacency build (single block, 1024 threads, te staged in LDS)
// ---------------------------------------------------------------------------
__global__ __launch_bounds__(1024) void k_adj(
    const float* __restrict__ sc, const float* __restrict__ te,
    const float* __restrict__ alpha_p, const float* __restrict__ dist,
    float* __restrict__ adj)
{
  __shared__ float tes[25][517];
  __shared__ float als[625];
  __shared__ float dots[625];
  __shared__ float scratch[16];
  __shared__ float mxs;
  int tid = threadIdx.x;

  for (int idx = tid; idx < 12800; idx += 1024)
    tes[idx >> 9][idx & 511] = te[idx];
  __syncthreads();

  if (tid < 625) {
    int i = tid / 25, j = tid % 25;
    float s = 0.f;
    for (int gq = 0; gq < 256; gq++) s += sc[(size_t)gq * 640 + tid];
    als[tid] = s * (1.f / 256.f);
    float dt = 0.f;
    const float* ti = tes[i];
    const float* tj = tes[j];
    for (int d = 0; d < 512; d++) dt += ti[d] * tj[d];
    dots[tid] = dt;
  }
  __syncthreads();
  float alpha = alpha_p[0];
  float lm = 0.f;
  if (tid < 625) {
    int i = tid / 25, j = tid % 25;
    float ni = 1.f / fmaxf(sqrtf(dots[i * 26]), 1e-8f);
    float nj = 1.f / fmaxf(sqrtf(dots[j * 26]), 1e-8f);
    float emb = dots[tid] * ni * nj;
    float a = (alpha * dist[tid] + (1.f - alpha) * emb) * als[tid];
    als[tid] = a;
    lm = powf(fmaxf(a, 0.f), 2.5f);
  }
  #pragma unroll
  for (int off = 32; off > 0; off >>= 1) lm = fmaxf(lm, __shfl_down(lm, off));
  int w = tid >> 6;
  if ((tid & 63) == 0) scratch[w] = lm;
  __syncthreads();
  if (tid == 0) {
    float m2 = scratch[0];
    for (int i = 1; i < 16; i++) m2 = fmaxf(m2, scratch[i]);
    mxs = m2;
  }
  __syncthreads();
  if (tid < 625) {
    float a = als[tid];
    float m = powf(fmaxf(a, 0.f), 2.5f) / mxs;
    adj[tid] = (m >= 0.08f) ? a : 0.f;
  }
}

// ---------------------------------------------------------------------------
// K7: GCN adjacency mix
// ---------------------------------------------------------------------------
template<int RESID, int LNORM>
__global__ __launch_bounds__(256) void k_mix(
    const float* __restrict__ adj, const float* __restrict__ tmp,
    const float* __restrict__ bias, const float* __restrict__ resid,
    const float* __restrict__ g, const float* __restrict__ be,
    float* __restrict__ out)
{
  __shared__ float adjs[25];
  __shared__ float scratch[8];
  int row = blockIdx.x;
  int b = row / 25, i = row % 25;
  int f = threadIdx.x;
  if (f < 25) adjs[f] = adj[f * 25 + i];
  __syncthreads();
  float acc = bias[f];
  const float* tp = tmp + (size_t)b * 25 * 256 + f;
  #pragma unroll 5
  for (int j = 0; j < 25; j++) acc += adjs[j] * tp[(size_t)j * 256];
  if (RESID) acc += resid[(size_t)row * 256 + f];
  float v = acc;
  if (LNORM) {
    float s = v, q = v * v;
    block_reduce2(s, q, scratch);
    float mean = s * (1.f / 256.f);
    float var = q * (1.f / 256.f) - mean * mean;
    v = (v - mean) * rsqrtf(var + 1e-5f) * g[f] + be[f];
  }
  out[(size_t)row * 256 + f] = fmaxf(v, 0.f);
}

// ---------------------------------------------------------------------------
// launch
// ---------------------------------------------------------------------------
extern "C" void kernel_launch(void* const* d_in, const int* in_sizes, int n_in,
                              void* d_out, int out_size, void* d_ws, size_t ws_size,
                              hipStream_t stream)
{
  (void)in_sizes; (void)n_in; (void)out_size; (void)ws_size;

  const float* x         = (const float*)d_in[0];
  const float* seq1_w1   = (const float*)d_in[1];
  const float* seq1_b1   = (const float*)d_in[2];
  const float* seq1_w2   = (const float*)d_in[3];
  const float* seq1_b2   = (const float*)d_in[4];
  const float* ln2_g     = (const float*)d_in[5];
  const float* ln2_b     = (const float*)d_in[6];
  const float* gru_wih_f = (const float*)d_in[7];
  const float* gru_whh_f = (const float*)d_in[8];
  const float* gru_bih_f = (const float*)d_in[9];
  const float* gru_bhh_f = (const float*)d_in[10];
  const float* gru_wih_b = (const float*)d_in[11];
  const float* gru_whh_b = (const float*)d_in[12];
  const float* gru_bih_b = (const float*)d_in[13];
  const float* gru_bhh_b = (const float*)d_in[14];
  const float* ln_g      = (const float*)d_in[15];
  const float* ln_b      = (const float*)d_in[16];
  const float* attn_in_w = (const float*)d_in[17];
  const float* attn_in_b = (const float*)d_in[18];
  const float* fc_ta_w   = (const float*)d_in[19];
  const float* fc_ta_b   = (const float*)d_in[20];
  const float* ln3_g     = (const float*)d_in[21];
  const float* ln3_b     = (const float*)d_in[22];
  const float* sem_embs  = (const float*)d_in[23];
  const float* sem_w     = (const float*)d_in[24];
  const float* sem_b     = (const float*)d_in[25];
  const float* lnsem_g   = (const float*)d_in[26];
  const float* lnsem_b   = (const float*)d_in[27];
  const float* att_alpha = (const float*)d_in[28];
  const float* dist_adj  = (const float*)d_in[29];
  const float* gcn_w0    = (const float*)d_in[30];
  const float* gcn_b0    = (const float*)d_in[31];
  const float* gcn_w1    = (const float*)d_in[32];
  const float* gcn_b1    = (const float*)d_in[33];
  const float* gcn_w2    = (const float*)d_in[34];
  const float* gcn_b2    = (const float*)d_in[35];
  const float* gln1_g    = (const float*)d_in[36];
  const float* gln1_b    = (const float*)d_in[37];
  const float* gln2_g    = (const float*)d_in[38];
  const float* gln2_b    = (const float*)d_in[39];
  const float* enc_ln_g  = (const float*)d_in[40];
  const float* enc_ln_b  = (const float*)d_in[41];
  const float* fc_w      = (const float*)d_in[42];
  const float* fc_b      = (const float*)d_in[43];

  float* w = (float*)d_ws;
  ushort_t* hseqb = (ushort_t*)(w + O_HSEQB);
  ushort_t* wb    = (ushort_t*)(w + O_WB);
  float* hf32 = w + O_HF32;
  ushort_t* hring = (ushort_t*)(w + O_HRING);
  float* hn   = w + O_HN;
  float* qkv  = w + O_QKV;
  float* sc   = w + O_SC;
  float* adjw = w + O_ADJ;
  float* wr   = w + O_WR;
  float* tep  = w + O_TEP;
  float* te   = w + O_TE;
  float* xcat = w + O_XCAT;
  float* gtmp = w + O_GTMP;
  float* xg0  = w + O_XG0;
  float* xg1  = w + O_XG1;
  float* xg2  = w + O_XG2;
  ushort_t* w1tb = (ushort_t*)(w + O_W1TB);
  ushort_t* w2tb = (ushort_t*)(w + O_W2TB);
  ushort_t* awb  = (ushort_t*)(w + O_AWB);
  ushort_t* ftwb = (ushort_t*)(w + O_FTWB);
  ushort_t* smwb = (ushort_t*)(w + O_SMWB);
  ushort_t* g0wb = (ushort_t*)(w + O_G0WB);
  ushort_t* g1wb = (ushort_t*)(w + O_G1WB);
  ushort_t* g2wb = (ushort_t*)(w + O_G2WB);
  ushort_t* fcwb = (ushort_t*)(w + O_FCWB);
  int* flags = (int*)(w + O_FLAGS);

  // zero h ring slot 0 (both dirs) + chain flags + XCD queue counters
  hipMemsetAsync(hring, 0, (size_t)819200 * sizeof(ushort_t), stream);
  hipMemsetAsync(flags, 0, 512 * sizeof(int), stream);

  // ---- weight conversions (2 launches) ----
  k_cvt_plain_all<<<3072, 256, 0, stream>>>(gru_wih_f, gru_whh_f, gru_wih_b,
                                            gru_whh_b, attn_in_w, wb, awb);
  {
    TJob j0 = {seq1_w1, w1tb, 100, 256, 128, 0};       //  32 tiles
    TJob j1 = {seq1_w2, w2tb, 256, 512, 256, 32};      // 128
    TJob j2 = {fc_ta_w, ftwb, 1024, 512, 1024, 160};   // 512
    TJob j3 = {sem_w, smwb, 768, 512, 768, 672};       // 384
    TJob j4 = {gcn_w0, g0wb, 1024, 256, 1024, 1056};   // 256
    TJob j5 = {gcn_w1, g1wb, 256, 256, 256, 1312};     //  64
    TJob j6 = {gcn_w2, g2wb, 256, 256, 256, 1376};     //  64
    TJob j7 = {fc_w, fcwb, 1280, 512, 1280, 1440};     // 640 -> total 2080
    k_cvt_t_all<<<2080, 256, 0, stream>>>(j0, j1, j2, j3, j4, j5, j6, j7);
  }

  // ---- input MLP + LN (all-MFMA, fused) ----
  k_mlp_fused<<<750, 256, 0, stream>>>(x, w1tb, seq1_b1, w2tb, seq1_b2,
                                       ln2_g, ln2_b, hseqb);

  // ---- bidirectional GRU: ONE persistent launch, 2 blocks/CU, L2 flags ----
  k_gru_persist<<<512, 256, 0, stream>>>(
      hseqb, wb, gru_bih_f, gru_bhh_f, gru_bih_b, gru_bhh_b, hf32, hring, flags);

  // hn = LN(concat(hf, hb))
  k_ln_hn<<<800, 256, 0, stream>>>(hf32, hf32 + 409600, ln_g, ln_b, hn);

  // q,k projection
  k_bgemm<0><<<dim3(32, 13), 256, 0, stream>>>(
      hn, awb, attn_in_b, qkv, 800, 2048, 1024, 1024, 2048);

  // per (b,h) softmax attention
  k_scores<<<dim3(32, 8), 256, 0, stream>>>(qkv, sc);

  // semantic embedding projection + LN
  k_bgemm<0><<<dim3(8, 1), 256, 0, stream>>>(
      sem_embs, smwb, sem_b, tep, 25, 512, 768, 768, 512);
  k_ln_rows<2><<<25, 256, 0, stream>>>(tep, te, lnsem_g, lnsem_b, 512, 0);

  // fc_ta + LN3 -> Xcat[:, 0:512]
  k_bgemm<1><<<dim3(8, 13), 256, 0, stream>>>(
      hn, ftwb, fc_ta_b, wr, 800, 512, 1024, 1024, 512);
  k_ln_rows<2><<<800, 256, 0, stream>>>(wr, xcat, ln3_g, ln3_b, 1280, 0);
  k_bcast_te<<<800, 256, 0, stream>>>(te, xcat);

  // adjacency
  k_adj<<<1, 1024, 0, stream>>>(sc, te, att_alpha, dist_adj, adjw);

  // GCN layer 0
  k_bgemm<0><<<dim3(4, 13), 256, 0, stream>>>(
      xcat, g0wb, nullptr, gtmp, 800, 256, 1024, 1280, 256);
  k_mix<0, 0><<<800, 256, 0, stream>>>(adjw, gtmp, gcn_b0, nullptr, nullptr, nullptr, xg0);
  // GCN layer 1
  k_bgemm<0><<<dim3(4, 13), 256, 0, stream>>>(
      xg0, g1wb, nullptr, gtmp, 800, 256, 256, 256, 256);
  k_mix<1, 1><<<800, 256, 0, stream>>>(adjw, gtmp, gcn_b1, xg0, gln1_g, gln1_b, xg1);
  // GCN layer 2
  k_bgemm<0><<<dim3(4, 13), 256, 0, stream>>>(
      xg1, g2wb, nullptr, gtmp, 800, 256, 256, 256, 256);
  k_mix<1, 1><<<800, 256, 0, stream>>>(adjw, gtmp, gcn_b2, xg1, gln2_g, gln2_b, xg2);

  // encoder LN -> Xcat[:, 1024:1280]
  k_ln_rows<1><<<800, 256, 0, stream>>>(xg2, xcat, enc_ln_g, enc_ln_b, 1280, 1024);

  // final fc + relu -> d_out
  k_bgemm<1><<<dim3(8, 13), 256, 0, stream>>>(
      xcat, fcwb, fc_b, (float*)d_out, 800, 512, 1280, 1280, 512);
}

// Round 15
// 1411.043 us; speedup vs baseline: 1.7027x; 1.7027x over previous
//
#include <hip/hip_runtime.h>
#include <hip/hip_bf16.h>
#include <math.h>

// ---------------------------------------------------------------------------
// Problem constants
// ---------------------------------------------------------------------------
#define BB 32
#define SS 60
#define NN_ 25
#define DIN 100
#define BN 800           // B*N
#define GRU_H 512
#define FDIM 1024        // TEMB+SEMB
#define CH 256
#define OUTD 512

typedef unsigned short ushort_t;
typedef unsigned int u32;
typedef unsigned long long u64;
typedef float f32x4 __attribute__((ext_vector_type(4)));
typedef __bf16 bf16x8 __attribute__((ext_vector_type(8)));
typedef short s16x8 __attribute__((ext_vector_type(8)));

// workspace float offsets
static const size_t O_HSEQB = 0;          // bf16 48000*512 = 12,288,000 fl
static const size_t O_WB    = 12288000;   // bf16 GRU weights, 1,572,864 fl
static const size_t O_HF32  = 13860864;   // fp32 [dir][800*512] final hidden
static const size_t O_HRING = 14680064;   // bf16 ring3 [slot][dir][800*512]
static const size_t O_HN    = 15908864;
static const size_t O_QKV   = 16728064;
static const size_t O_SC    = 18366464;
static const size_t O_ADJ   = 18530304;
static const size_t O_WR    = 18530944;
static const size_t O_TEP   = 18940544;
static const size_t O_TE    = 18953344;
static const size_t O_XCAT  = 18966144;
static const size_t O_GTMP  = 19990144;
static const size_t O_XG0   = 20194944;
static const size_t O_XG1   = 20399744;
static const size_t O_XG2   = 20604544;
// bf16 weight buffers (pre-transposed to [N][K])
static const size_t O_W1TB  = 20809344;   // 256x128
static const size_t O_W2TB  = 20825728;   // 512x256
static const size_t O_AWB   = 20891264;   // 2048x1024
static const size_t O_FTWB  = 21939840;   // 512x1024
static const size_t O_SMWB  = 22201984;   // 512x768
static const size_t O_G0WB  = 22398592;   // 256x1024
static const size_t O_G1WB  = 22529664;   // 256x256
static const size_t O_G2WB  = 22562432;   // 256x256
static const size_t O_FCWB  = 22595200;   // 512x1280
static const size_t O_FLAGS = 22922880;   // 26 chain flags (16-int stride) + 8 XCD queue counters @ +448

__device__ __forceinline__ ushort_t f2b(float v)
{
  __hip_bfloat16 b = __float2bfloat16(v);
  return *reinterpret_cast<ushort_t*>(&b);
}

__device__ __forceinline__ float sig_fast(float v)
{
  return 1.f / (1.f + __expf(-v));
}
__device__ __forceinline__ float tanh_fast(float v)
{
  return 1.f - 2.f / (1.f + __expf(2.f * v));
}

__device__ __forceinline__ void block_reduce2(float& s, float& q, float* scratch)
{
  __syncthreads();
  #pragma unroll
  for (int off = 32; off > 0; off >>= 1) {
    s += __shfl_down(s, off);
    q += __shfl_down(q, off);
  }
  int tid = threadIdx.x;
  int w = tid >> 6;
  if ((tid & 63) == 0) { scratch[w * 2] = s; scratch[w * 2 + 1] = q; }
  __syncthreads();
  if (tid == 0) {
    float ss = 0.f, qq = 0.f;
    int nw = blockDim.x >> 6;
    for (int i = 0; i < nw; i++) { ss += scratch[i * 2]; qq += scratch[i * 2 + 1]; }
    scratch[0] = ss; scratch[1] = qq;
  }
  __syncthreads();
  s = scratch[0]; q = scratch[1];
}

// ---------------------------------------------------------------------------
// merged conversions
// ---------------------------------------------------------------------------
__global__ __launch_bounds__(256) void k_cvt_plain_all(
    const float* __restrict__ wih_f, const float* __restrict__ whh_f,
    const float* __restrict__ wih_b, const float* __restrict__ whh_b,
    const float* __restrict__ attn_w,
    ushort_t* __restrict__ wb, ushort_t* __restrict__ awb)
{
  int i = blockIdx.x * 256 + threadIdx.x;   // 0..786431
  wb[i]           = f2b(wih_f[i]);
  wb[786432 + i]  = f2b(whh_f[i]);
  wb[1572864 + i] = f2b(wih_b[i]);
  wb[2359296 + i] = f2b(whh_b[i]);
  awb[i]          = f2b(attn_w[i]);
  awb[786432 + i] = f2b(attn_w[786432 + i]);
  int j = 1572864 + i;
  if (j < 2097152) awb[j] = f2b(attn_w[j]);
}

struct TJob {
  const float* src; ushort_t* dst;
  int K, N, KP, base;
};

// transpose [K][N] fp32 -> [N][KP] bf16, 8 jobs, one launch
__global__ __launch_bounds__(256) void k_cvt_t_all(
    TJob j0, TJob j1, TJob j2, TJob j3, TJob j4, TJob j5, TJob j6, TJob j7)
{
  __shared__ float tile[32][33];
  int t = blockIdx.x;
  TJob jb = j0;
  if (t >= j7.base) jb = j7;
  else if (t >= j6.base) jb = j6;
  else if (t >= j5.base) jb = j5;
  else if (t >= j4.base) jb = j4;
  else if (t >= j3.base) jb = j3;
  else if (t >= j2.base) jb = j2;
  else if (t >= j1.base) jb = j1;
  int local = t - jb.base;
  int ktiles = (jb.KP + 31) >> 5;
  int n0 = (local / ktiles) * 32;
  int k0 = (local % ktiles) * 32;
  int tx = threadIdx.x & 31, ty = threadIdx.x >> 5;
  #pragma unroll
  for (int i = 0; i < 4; i++) {
    int k = k0 + ty + i * 8, n = n0 + tx;
    tile[ty + i * 8][tx] = (k < jb.K && n < jb.N) ? jb.src[(size_t)k * jb.N + n] : 0.f;
  }
  __syncthreads();
  #pragma unroll
  for (int i = 0; i < 4; i++) {
    int n = n0 + ty + i * 8, k = k0 + tx;
    if (n < jb.N && k < jb.KP) jb.dst[(size_t)n * jb.KP + k] = f2b(tile[tx][ty + i * 8]);
  }
}

// ---------------------------------------------------------------------------
// K1: fused MLP (100->256 relu -> 512 relu) + LN(512), all-MFMA, bf16 out.
// ---------------------------------------------------------------------------
__global__ __launch_bounds__(256, 1) void k_mlp_fused(
    const float* __restrict__ x,
    const ushort_t* __restrict__ w1tb,   // [256][128]
    const float* __restrict__ b1,
    const ushort_t* __restrict__ w2tb,   // [512][256]
    const float* __restrict__ b2,
    const float* __restrict__ g, const float* __restrict__ be,
    ushort_t* __restrict__ hseqb)
{
  __shared__ __align__(16) ushort_t xb[64][136];
  __shared__ __align__(16) ushort_t Bl[512][40];
  __shared__ __align__(16) ushort_t h1[64][264];
  const int tid = threadIdx.x;
  const int r0 = blockIdx.x * 64;

  {
    int rr = tid >> 2;
    int d0 = (tid & 3) * 32;
    int r = r0 + rr;
    int bn = r / SS, s = r % SS;
    int b = bn / NN_, n = bn % NN_;
    const float* xp = x + (((size_t)b * SS + s) * NN_ + n) * DIN;
    ushort_t tmp[32];
    #pragma unroll
    for (int i = 0; i < 32; i++) {
      int d = d0 + i;
      tmp[i] = (d < DIN) ? f2b(xp[d]) : (ushort_t)0;
    }
    #pragma unroll
    for (int i = 0; i < 4; i++)
      *reinterpret_cast<s16x8*>(&xb[rr][d0 + i * 8]) = *reinterpret_cast<s16x8*>(&tmp[i * 8]);
  }
  const int wid = tid >> 6, l = tid & 63, lr = l & 15, lg = l >> 4;
  const int srow = tid >> 2, skg = (tid & 3) * 8;

  // ---- layer 1: 64x256, K=128 ----
  f32x4 acc1[16] = {};
  for (int kc = 0; kc < 4; kc++) {
    __syncthreads();
    #pragma unroll
    for (int i = 0; i < 4; i++) {
      int row = srow + i * 64;
      *reinterpret_cast<s16x8*>(&Bl[row][skg]) =
          *reinterpret_cast<const s16x8*>(w1tb + (size_t)row * 128 + kc * 32 + skg);
    }
    __syncthreads();
    bf16x8 aF = *reinterpret_cast<const bf16x8*>(&xb[wid * 16 + lr][kc * 32 + lg * 8]);
    #pragma unroll
    for (int ni = 0; ni < 16; ni++) {
      bf16x8 bF = *reinterpret_cast<const bf16x8*>(&Bl[ni * 16 + lr][lg * 8]);
      acc1[ni] = __builtin_amdgcn_mfma_f32_16x16x32_bf16(aF, bF, acc1[ni], 0, 0, 0);
    }
  }
  #pragma unroll
  for (int ni = 0; ni < 16; ni++) {
    #pragma unroll
    for (int r = 0; r < 4; r++) {
      int row = wid * 16 + lg * 4 + r;
      int col = ni * 16 + lr;
      h1[row][col] = f2b(fmaxf(acc1[ni][r] + b1[col], 0.f));
    }
  }

  // ---- layer 2: 64x512, K=256 ----
  f32x4 acc2[32] = {};
  for (int kc = 0; kc < 8; kc++) {
    __syncthreads();
    #pragma unroll
    for (int i = 0; i < 8; i++) {
      int row = srow + i * 64;
      *reinterpret_cast<s16x8*>(&Bl[row][skg]) =
          *reinterpret_cast<const s16x8*>(w2tb + (size_t)row * 256 + kc * 32 + skg);
    }
    __syncthreads();
    bf16x8 aF = *reinterpret_cast<const bf16x8*>(&h1[wid * 16 + lr][kc * 32 + lg * 8]);
    #pragma unroll
    for (int ni = 0; ni < 32; ni++) {
      bf16x8 bF = *reinterpret_cast<const bf16x8*>(&Bl[ni * 16 + lr][lg * 8]);
      acc2[ni] = __builtin_amdgcn_mfma_f32_16x16x32_bf16(aF, bF, acc2[ni], 0, 0, 0);
    }
  }

  // ---- bias + relu + in-register LN over 512 ----
  float su[4] = {0.f, 0.f, 0.f, 0.f}, sq[4] = {0.f, 0.f, 0.f, 0.f};
  #pragma unroll
  for (int ni = 0; ni < 32; ni++) {
    float bb = b2[ni * 16 + lr];
    #pragma unroll
    for (int r = 0; r < 4; r++) {
      float v = fmaxf(acc2[ni][r] + bb, 0.f);
      acc2[ni][r] = v;
      su[r] += v; sq[r] += v * v;
    }
  }
  #pragma unroll
  for (int off = 1; off < 16; off <<= 1) {
    #pragma unroll
    for (int r = 0; r < 4; r++) {
      su[r] += __shfl_xor(su[r], off);
      sq[r] += __shfl_xor(sq[r], off);
    }
  }
  #pragma unroll
  for (int r = 0; r < 4; r++) {
    float mean = su[r] * (1.f / 512.f);
    float var = sq[r] * (1.f / 512.f) - mean * mean;
    float rs = rsqrtf(var + 1e-5f);
    int rowg = r0 + wid * 16 + lg * 4 + r;
    ushort_t* outp = hseqb + (size_t)rowg * 512;
    #pragma unroll
    for (int ni = 0; ni < 32; ni++) {
      int col = ni * 16 + lr;
      outp[col] = f2b((acc2[ni][r] - mean) * rs * g[col] + be[col]);
    }
  }
}

// ---------------------------------------------------------------------------
// K2: PERSISTENT GRU, 60 steps, one launch. v5 (= v3/R10 + pipeline fixes):
//   - weights GLOBAL -> MFMA fragment, EXPLICIT 1-deep register double-buffer
//     (prefetch iter it+1's 6 B-frags before MFMA of iter it).
//   - x,h staged full-K into LDS once/step; ZERO inner-loop barriers.
//   - s_setprio(1) around each MFMA cluster (waves drift -> role diversity).
//   - chain flags at the LOCAL XCD L2 (workgroup-scope add + volatile poll;
//     sound because XCC_ID work-claim pins a chain's 8 writers to one XCD).
//   - XCC_ID work-claim, ring-3 h buffer, <=1-step skew.
// ---------------------------------------------------------------------------
__global__ __launch_bounds__(256, 1) void k_gru_persist(
    const ushort_t* __restrict__ hseqb, const ushort_t* __restrict__ wb,
    const float* __restrict__ bih_f, const float* __restrict__ bhh_f,
    const float* __restrict__ bih_b, const float* __restrict__ bhh_b,
    float* __restrict__ hf32, ushort_t* __restrict__ hring,
    int* __restrict__ flags)
{
  __shared__ __align__(16) ushort_t Xf[64][520];   // 66.6 KB full-K x
  __shared__ __align__(16) ushort_t Hf[64][520];   // 66.6 KB full-K h
  __shared__ __align__(16) ushort_t hpack[64][72]; // 9.2 KB pack buffer
  __shared__ int s_item;

  const int tid = threadIdx.x;

  // ---- XCD-local work claim ----
  int* qcnt = flags + 448;   // 8 counters
  if (tid == 0) {
    u32 xcc;
    asm volatile("s_getreg_b32 %0, hwreg(HW_REG_XCC_ID)" : "=s"(xcc));
    xcc &= 7u;
    int idx = __hip_atomic_fetch_add(qcnt + xcc, 1, __ATOMIC_RELAXED,
                                     __HIP_MEMORY_SCOPE_AGENT);
    s_item = (idx << 3) | (int)xcc;
  }
  __syncthreads();
  const int xcd = s_item & 7;
  const int idx = s_item >> 3;
  const int x3 = xcd & 3;
  const int dir = xcd >> 2;
  const int nmt = (x3 == 0) ? 4 : 3;      // mt in {x3, x3+4, x3+8[, x3+12]} < 13
  if (idx >= nmt * 8) return;             // surplus block on this XCD
  const int mt = (idx >> 3) * 4 + x3;
  const int jt = idx & 7;
  const int j0g = jt * 64;
  const int m0g = mt * 64;
  const int chain = dir * 13 + mt;        // 26 chains x 8 writer blocks
  int* flagp = flags + chain * 16;

  const ushort_t* __restrict__ wih = wb + (size_t)dir * 1572864;
  const ushort_t* __restrict__ whh = wih + 786432;
  const float* __restrict__ bih = dir ? bih_b : bih_f;
  const float* __restrict__ bhh = dir ? bhh_b : bhh_f;
  const size_t dirOff = (size_t)dir * 409600;

  const int srow = tid >> 2;          // staging row 0..63
  const int skg  = (tid & 3) * 8;     // staging k offset (x8 ushort)
  const int smg  = m0g + srow;
  const int smg_c = (smg < BN) ? smg : 0;

  const int wid = tid >> 6;
  const int l = tid & 63;
  const int lr = l & 15;
  const int lg = l >> 4;
  const int jg = j0g + (wid << 4) + lr;   // this thread's output column j

  // per-gate weight fragment pointers (per-lane, constant across steps)
  const ushort_t* pwf[6];
  #pragma unroll
  for (int tt = 0; tt < 6; tt++) {
    const ushort_t* src = (tt < 3) ? wih : whh;
    int gate = (tt < 3) ? tt : tt - 3;
    pwf[tt] = src + ((size_t)(gate * 512 + jg) * 512) + lg * 8;
  }

  // hoisted per-column biases (j fixed per thread)
  const float rbr  = bih[jg] + bhh[jg];
  const float rbz  = bih[512 + jg] + bhh[512 + jg];
  const float rbin = bih[1024 + jg];
  const float rbhn = bhh[1024 + jg];

  // h carried in registers (block owns the same 64x64 slice every step)
  float hpreg[4][4] = {};   // [mi][r]

  for (int t = 0; t < SS; ++t) {
    const int xt = dir ? (SS - 1 - t) : t;
    const ushort_t* __restrict__ hprev = hring + (size_t)(t % 3) * 819200 + dirOff;
    ushort_t* __restrict__ hnew = hring + (size_t)((t + 1) % 3) * 819200 + dirOff;
    const ushort_t* __restrict__ px = hseqb + ((size_t)smg_c * SS + xt) * 512 + skg;

    // ---- x loads (independent of h): issue BEFORE flag wait ----
    s16x8 rxv[16];
    #pragma unroll
    for (int c = 0; c < 16; c++)
      rxv[c] = *reinterpret_cast<const s16x8*>(px + c * 32);

    // ---- chain-flag wait (volatile poll -> local XCD L2) ----
    if (t > 0 && tid == 0) {
      while (*(volatile const int*)flagp < 8 * t) {
        __builtin_amdgcn_s_sleep(2);
      }
    }
    __syncthreads();   // (A) flag seen by all; previous-step LDS readers done

    // ---- stage h (volatile, L1-bypass -> local-XCD L2) + x into LDS ----
    {
      const ushort_t* ph = hprev + (size_t)smg_c * 512 + skg;
      u64 hv[32];
      #pragma unroll
      for (int c = 0; c < 16; c++) {
        hv[2 * c]     = *reinterpret_cast<const volatile u64*>(ph + c * 32);
        hv[2 * c + 1] = *reinterpret_cast<const volatile u64*>(ph + c * 32 + 4);
      }
      #pragma unroll
      for (int c = 0; c < 16; c++) {
        *reinterpret_cast<s16x8*>(&Xf[srow][c * 32 + skg]) = rxv[c];
        *reinterpret_cast<u64*>(&Hf[srow][c * 32 + skg])     = hv[2 * c];
        *reinterpret_cast<u64*>(&Hf[srow][c * 32 + skg + 4]) = hv[2 * c + 1];
      }
    }
    __syncthreads();   // (B) Xf/Hf ready; read-only below -> no more barriers

    f32x4 accr[4] = {};
    f32x4 accz[4] = {};
    f32x4 accin[4] = {};
    f32x4 acchn[4] = {};

    // prologue weight fragments (it = 0)
    bf16x8 bW[6];
    #pragma unroll
    for (int tt = 0; tt < 6; tt++)
      bW[tt] = *reinterpret_cast<const bf16x8*>(pwf[tt]);

    #pragma unroll 4
    for (int it = 0; it < 16; ++it) {
      const int k0 = it * 32;
      // explicit 1-deep double buffer: prefetch it+1's fragments NOW
      bf16x8 bN[6];
      if (it < 15) {
        #pragma unroll
        for (int tt = 0; tt < 6; tt++)
          bN[tt] = *reinterpret_cast<const bf16x8*>(pwf[tt] + k0 + 32);
      }
      bf16x8 xA[4], hA[4];
      #pragma unroll
      for (int mi = 0; mi < 4; mi++) {
        xA[mi] = *reinterpret_cast<const bf16x8*>(&Xf[mi * 16 + lr][k0 + lg * 8]);
        hA[mi] = *reinterpret_cast<const bf16x8*>(&Hf[mi * 16 + lr][k0 + lg * 8]);
      }
      __builtin_amdgcn_s_setprio(1);
      #pragma unroll
      for (int mi = 0; mi < 4; mi++) {
        accr[mi]  = __builtin_amdgcn_mfma_f32_16x16x32_bf16(xA[mi], bW[0], accr[mi], 0, 0, 0);
        accr[mi]  = __builtin_amdgcn_mfma_f32_16x16x32_bf16(hA[mi], bW[3], accr[mi], 0, 0, 0);
        accz[mi]  = __builtin_amdgcn_mfma_f32_16x16x32_bf16(xA[mi], bW[1], accz[mi], 0, 0, 0);
        accz[mi]  = __builtin_amdgcn_mfma_f32_16x16x32_bf16(hA[mi], bW[4], accz[mi], 0, 0, 0);
        accin[mi] = __builtin_amdgcn_mfma_f32_16x16x32_bf16(xA[mi], bW[2], accin[mi], 0, 0, 0);
        acchn[mi] = __builtin_amdgcn_mfma_f32_16x16x32_bf16(hA[mi], bW[5], acchn[mi], 0, 0, 0);
      }
      __builtin_amdgcn_s_setprio(0);
      if (it < 15) {
        #pragma unroll
        for (int tt = 0; tt < 6; tt++) bW[tt] = bN[tt];
      }
    }

    // ---- gate epilogue: update register-resident h ----
    #pragma unroll
    for (int mi = 0; mi < 4; mi++) {
      #pragma unroll
      for (int r = 0; r < 4; r++) {
        float sr = accr[mi][r] + rbr;
        float sz = accz[mi][r] + rbz;
        float rg = sig_fast(sr);
        float zg = sig_fast(sz);
        float ng = tanh_fast(accin[mi][r] + rbin + rg * (acchn[mi][r] + rbhn));
        hpreg[mi][r] = (1.f - zg) * ng + zg * hpreg[mi][r];
      }
    }

    if (t < SS - 1) {
      // pack h_new bf16, coalesced 16B stores to local L2
      #pragma unroll
      for (int mi = 0; mi < 4; mi++)
        #pragma unroll
        for (int r = 0; r < 4; r++)
          hpack[mi * 16 + lg * 4 + r][(wid << 4) + lr] = f2b(hpreg[mi][r]);
      __syncthreads();   // (D)
      {
        int row = tid >> 2;
        int gm = m0g + row;
        if (gm < BN) {
          ushort_t* dst = hnew + (size_t)gm * 512 + j0g + (tid & 3) * 16;
          *reinterpret_cast<s16x8*>(dst) =
              *reinterpret_cast<s16x8*>(&hpack[row][(tid & 3) * 16]);
          *reinterpret_cast<s16x8*>(dst + 8) =
              *reinterpret_cast<s16x8*>(&hpack[row][(tid & 3) * 16 + 8]);
        }
      }
      __syncthreads();   // (E) drains vmcnt(0): stores in L2 before flag add
      if (tid == 0)
        __hip_atomic_fetch_add(flagp, 1, __ATOMIC_RELAXED, __HIP_MEMORY_SCOPE_WORKGROUP);
    } else {
      // final step: write fp32 hidden for k_ln_hn
      float* hfin = hf32 + dirOff;
      #pragma unroll
      for (int mi = 0; mi < 4; mi++) {
        #pragma unroll
        for (int r = 0; r < 4; r++) {
          int m = m0g + mi * 16 + lg * 4 + r;
          if (m < BN) hfin[(size_t)m * 512 + jg] = hpreg[mi][r];
        }
      }
    }
  }
}

// ---------------------------------------------------------------------------
// K3: hn = LN(concat(hf, hb)) over 1024.
// ---------------------------------------------------------------------------
__global__ __launch_bounds__(256) void k_ln_hn(
    const float* __restrict__ hf, const float* __restrict__ hb,
    const float* __restrict__ g, const float* __restrict__ be,
    float* __restrict__ hn)
{
  __shared__ float scratch[8];
  int row = blockIdx.x, tid = threadIdx.x;
  float v[4];
  float s = 0.f, q = 0.f;
  #pragma unroll
  for (int p = 0; p < 4; p++) {
    int c = p * 256 + tid;
    float val = (c < 512) ? hf[(size_t)row * 512 + c] : hb[(size_t)row * 512 + (c - 512)];
    v[p] = val; s += val; q += val * val;
  }
  block_reduce2(s, q, scratch);
  float mean = s * (1.f / 1024.f);
  float var = q * (1.f / 1024.f) - mean * mean;
  float rs = rsqrtf(var + 1e-5f);
  #pragma unroll
  for (int p = 0; p < 4; p++) {
    int c = p * 256 + tid;
    hn[(size_t)row * 1024 + c] = (v[p] - mean) * rs * g[c] + be[c];
  }
}

// ---------------------------------------------------------------------------
// bf16 MFMA GEMM: C = act(bias + A(fp32,cvt) @ B(bf16,[N][K])^T)
// ---------------------------------------------------------------------------
template<int ACT>
__global__ __launch_bounds__(256) void k_bgemm(
    const float* __restrict__ A, const ushort_t* __restrict__ B,
    const float* __restrict__ bias, float* __restrict__ C,
    int M, int N, int K, int lda, int ldc)
{
  __shared__ __align__(16) ushort_t Al[64][40];
  __shared__ __align__(16) ushort_t Bl[64][40];
  const int tid = threadIdx.x;
  const int n0g = blockIdx.x * 64, m0g = blockIdx.y * 64;
  const int srow = tid >> 2, skg = (tid & 3) * 8;
  const int smg = (m0g + srow < M) ? (m0g + srow) : (M - 1);
  const int sng = (n0g + srow < N) ? (n0g + srow) : (N - 1);
  const float* pa = A + (size_t)smg * lda + skg;
  const ushort_t* pb = B + (size_t)sng * K + skg;
  const int wid = tid >> 6, l = tid & 63, lr = l & 15, lg = l >> 4;
  const int mbase = (wid >> 1) * 32, nbase = (wid & 1) * 32;
  f32x4 acc[2][2] = {};

  for (int k0 = 0; k0 < K; k0 += 32) {
    float4 a0 = *reinterpret_cast<const float4*>(pa + k0);
    float4 a1 = *reinterpret_cast<const float4*>(pa + k0 + 4);
    s16x8 bv = *reinterpret_cast<const s16x8*>(pb + k0);
    ushort_t tmp[8] = {f2b(a0.x), f2b(a0.y), f2b(a0.z), f2b(a0.w),
                       f2b(a1.x), f2b(a1.y), f2b(a1.z), f2b(a1.w)};
    *reinterpret_cast<s16x8*>(&Al[srow][skg]) = *reinterpret_cast<s16x8*>(tmp);
    *reinterpret_cast<s16x8*>(&Bl[srow][skg]) = bv;
    __syncthreads();
    bf16x8 aF[2], bF[2];
    #pragma unroll
    for (int mi = 0; mi < 2; mi++)
      aF[mi] = *reinterpret_cast<const bf16x8*>(&Al[mbase + mi * 16 + lr][lg * 8]);
    #pragma unroll
    for (int ni = 0; ni < 2; ni++)
      bF[ni] = *reinterpret_cast<const bf16x8*>(&Bl[nbase + ni * 16 + lr][lg * 8]);
    #pragma unroll
    for (int mi = 0; mi < 2; mi++)
      #pragma unroll
      for (int ni = 0; ni < 2; ni++)
        acc[mi][ni] = __builtin_amdgcn_mfma_f32_16x16x32_bf16(aF[mi], bF[ni], acc[mi][ni], 0, 0, 0);
    __syncthreads();
  }
  #pragma unroll
  for (int mi = 0; mi < 2; mi++) {
    #pragma unroll
    for (int r = 0; r < 4; r++) {
      int mg = m0g + mbase + mi * 16 + lg * 4 + r;
      if (mg >= M) continue;
      #pragma unroll
      for (int ni = 0; ni < 2; ni++) {
        int ng = n0g + nbase + ni * 16 + lr;
        if (ng >= N) continue;
        float v = acc[mi][ni][r] + (bias ? bias[ng] : 0.f);
        if (ACT == 1) v = fmaxf(v, 0.f);
        C[(size_t)mg * ldc + ng] = v;
      }
    }
  }
}

// ---------------------------------------------------------------------------
// K4: per (b,h) attention scores + softmax.
// ---------------------------------------------------------------------------
__global__ __launch_bounds__(256) void k_scores(const float* __restrict__ qkv,
                                                float* __restrict__ sc)
{
  int b = blockIdx.x, h = blockIdx.y;
  __shared__ float qs[25][128];
  __shared__ float ks[25][129];
  __shared__ float ps[25][26];
  int tid = threadIdx.x;
  for (int idx = tid; idx < 3200; idx += 256) {
    int i = idx >> 7, d = idx & 127;
    const float* base = qkv + (size_t)(b * 25 + i) * 2048 + h * 128 + d;
    qs[i][d] = base[0];
    ks[i][d] = base[1024];
  }
  __syncthreads();
  const float scale = 0.08838834764831845f;
  for (int e = tid; e < 625; e += 256) {
    int i = e / 25, j = e % 25;
    float s = 0.f;
    for (int d = 0; d < 128; d++) s += qs[i][d] * ks[j][d];
    ps[i][j] = s * scale;
  }
  __syncthreads();
  if (tid < 25) {
    float mx = -1e30f;
    for (int j = 0; j < 25; j++) mx = fmaxf(mx, ps[tid][j]);
    float s = 0.f;
    for (int j = 0; j < 25; j++) { float ev = expf(ps[tid][j] - mx); ps[tid][j] = ev; s += ev; }
    float inv = 1.f / s;
    for (int j = 0; j < 25; j++) ps[tid][j] *= inv;
  }
  __syncthreads();
  float* out = sc + (size_t)(b * 8 + h) * 640;
  for (int e = tid; e < 625; e += 256) out[e] = ps[e / 25][e % 25];
}

// ---------------------------------------------------------------------------
// K5: generic per-row LayerNorm (fp32 src/dst).
// ---------------------------------------------------------------------------
template<int PER>
__global__ __launch_bounds__(256) void k_ln_rows(
    const float* __restrict__ src, float* __restrict__ dst,
    const float* __restrict__ g, const float* __restrict__ be,
    int dstStride, int dstOff)
{
  __shared__ float scratch[8];
  int row = blockIdx.x, tid = threadIdx.x;
  const int C = PER * 256;
  float v[PER];
  float s = 0.f, q = 0.f;
  #pragma unroll
  for (int p = 0; p < PER; p++) {
    v[p] = src[(size_t)row * C + p * 256 + tid];
    s += v[p]; q += v[p] * v[p];
  }
  block_reduce2(s, q, scratch);
  float mean = s / (float)C;
  float var = q / (float)C - mean * mean;
  float rs = rsqrtf(var + 1e-5f);
  #pragma unroll
  for (int p = 0; p < PER; p++) {
    int c = p * 256 + tid;
    dst[(size_t)row * dstStride + dstOff + c] = (v[p] - mean) * rs * g[c] + be[c];
  }
}

__global__ __launch_bounds__(256) void k_bcast_te(const float* __restrict__ te,
                                                  float* __restrict__ xcat)
{
  int row = blockIdx.x, tid = threadIdx.x;
  int n = row % 25;
  xcat[(size_t)row * 1280 + 512 + tid] = te[n * 512 + tid];
  xcat[(size_t)row * 1280 + 768 + tid] = te[n * 512 + 256 + tid];
}

// ---------------------------------------------------------------------------
// K6: adjacency build (single block, 1024 threads, te staged in LDS)
// ---------------------------------------------------------------------------
__global__ __launch_bounds__(1024) void k_adj(
    const float* __restrict__ sc, const float* __restrict__ te,
    const float* __restrict__ alpha_p, const float* __restrict__ dist,
    float* __restrict__ adj)
{
  __shared__ float tes[25][517];
  __shared__ float als[625];
  __shared__ float dots[625];
  __shared__ float scratch[16];
  __shared__ float mxs;
  int tid = threadIdx.x;

  for (int idx = tid; idx < 12800; idx += 1024)
    tes[idx >> 9][idx & 511] = te[idx];
  __syncthreads();

  if (tid < 625) {
    int i = tid / 25, j = tid % 25;
    float s = 0.f;
    for (int gq = 0; gq < 256; gq++) s += sc[(size_t)gq * 640 + tid];
    als[tid] = s * (1.f / 256.f);
    float dt = 0.f;
    const float* ti = tes[i];
    const float* tj = tes[j];
    for (int d = 0; d < 512; d++) dt += ti[d] * tj[d];
    dots[tid] = dt;
  }
  __syncthreads();
  float alpha = alpha_p[0];
  float lm = 0.f;
  if (tid < 625) {
    int i = tid / 25, j = tid % 25;
    float ni = 1.f / fmaxf(sqrtf(dots[i * 26]), 1e-8f);
    float nj = 1.f / fmaxf(sqrtf(dots[j * 26]), 1e-8f);
    float emb = dots[tid] * ni * nj;
    float a = (alpha * dist[tid] + (1.f - alpha) * emb) * als[tid];
    als[tid] = a;
    lm = powf(fmaxf(a, 0.f), 2.5f);
  }
  #pragma unroll
  for (int off = 32; off > 0; off >>= 1) lm = fmaxf(lm, __shfl_down(lm, off));
  int w = tid >> 6;
  if ((tid & 63) == 0) scratch[w] = lm;
  __syncthreads();
  if (tid == 0) {
    float m2 = scratch[0];
    for (int i = 1; i < 16; i++) m2 = fmaxf(m2, scratch[i]);
    mxs = m2;
  }
  __syncthreads();
  if (tid < 625) {
    float a = als[tid];
    float m = powf(fmaxf(a, 0.f), 2.5f) / mxs;
    adj[tid] = (m >= 0.08f) ? a : 0.f;
  }
}

// ---------------------------------------------------------------------------
// K7: GCN adjacency mix
// ---------------------------------------------------------------------------
template<int RESID, int LNORM>
__global__ __launch_bounds__(256) void k_mix(
    const float* __restrict__ adj, const float* __restrict__ tmp,
    const float* __restrict__ bias, const float* __restrict__ resid,
    const float* __restrict__ g, const float* __restrict__ be,
    float* __restrict__ out)
{
  __shared__ float adjs[25];
  __shared__ float scratch[8];
  int row = blockIdx.x;
  int b = row / 25, i = row % 25;
  int f = threadIdx.x;
  if (f < 25) adjs[f] = adj[f * 25 + i];
  __syncthreads();
  float acc = bias[f];
  const float* tp = tmp + (size_t)b * 25 * 256 + f;
  #pragma unroll 5
  for (int j = 0; j < 25; j++) acc += adjs[j] * tp[(size_t)j * 256];
  if (RESID) acc += resid[(size_t)row * 256 + f];
  float v = acc;
  if (LNORM) {
    float s = v, q = v * v;
    block_reduce2(s, q, scratch);
    float mean = s * (1.f / 256.f);
    float var = q * (1.f / 256.f) - mean * mean;
    v = (v - mean) * rsqrtf(var + 1e-5f) * g[f] + be[f];
  }
  out[(size_t)row * 256 + f] = fmaxf(v, 0.f);
}

// ---------------------------------------------------------------------------
// launch
// ---------------------------------------------------------------------------
extern "C" void kernel_launch(void* const* d_in, const int* in_sizes, int n_in,
                              void* d_out, int out_size, void* d_ws, size_t ws_size,
                              hipStream_t stream)
{
  (void)in_sizes; (void)n_in; (void)out_size; (void)ws_size;

  const float* x         = (const float*)d_in[0];
  const float* seq1_w1   = (const float*)d_in[1];
  const float* seq1_b1   = (const float*)d_in[2];
  const float* seq1_w2   = (const float*)d_in[3];
  const float* seq1_b2   = (const float*)d_in[4];
  const float* ln2_g     = (const float*)d_in[5];
  const float* ln2_b     = (const float*)d_in[6];
  const float* gru_wih_f = (const float*)d_in[7];
  const float* gru_whh_f = (const float*)d_in[8];
  const float* gru_bih_f = (const float*)d_in[9];
  const float* gru_bhh_f = (const float*)d_in[10];
  const float* gru_wih_b = (const float*)d_in[11];
  const float* gru_whh_b = (const float*)d_in[12];
  const float* gru_bih_b = (const float*)d_in[13];
  const float* gru_bhh_b = (const float*)d_in[14];
  const float* ln_g      = (const float*)d_in[15];
  const float* ln_b      = (const float*)d_in[16];
  const float* attn_in_w = (const float*)d_in[17];
  const float* attn_in_b = (const float*)d_in[18];
  const float* fc_ta_w   = (const float*)d_in[19];
  const float* fc_ta_b   = (const float*)d_in[20];
  const float* ln3_g     = (const float*)d_in[21];
  const float* ln3_b     = (const float*)d_in[22];
  const float* sem_embs  = (const float*)d_in[23];
  const float* sem_w     = (const float*)d_in[24];
  const float* sem_b     = (const float*)d_in[25];
  const float* lnsem_g   = (const float*)d_in[26];
  const float* lnsem_b   = (const float*)d_in[27];
  const float* att_alpha = (const float*)d_in[28];
  const float* dist_adj  = (const float*)d_in[29];
  const float* gcn_w0    = (const float*)d_in[30];
  const float* gcn_b0    = (const float*)d_in[31];
  const float* gcn_w1    = (const float*)d_in[32];
  const float* gcn_b1    = (const float*)d_in[33];
  const float* gcn_w2    = (const float*)d_in[34];
  const float* gcn_b2    = (const float*)d_in[35];
  const float* gln1_g    = (const float*)d_in[36];
  const float* gln1_b    = (const float*)d_in[37];
  const float* gln2_g    = (const float*)d_in[38];
  const float* gln2_b    = (const float*)d_in[39];
  const float* enc_ln_g  = (const float*)d_in[40];
  const float* enc_ln_b  = (const float*)d_in[41];
  const float* fc_w      = (const float*)d_in[42];
  const float* fc_b      = (const float*)d_in[43];

  float* w = (float*)d_ws;
  ushort_t* hseqb = (ushort_t*)(w + O_HSEQB);
  ushort_t* wb    = (ushort_t*)(w + O_WB);
  float* hf32 = w + O_HF32;
  ushort_t* hring = (ushort_t*)(w + O_HRING);
  float* hn   = w + O_HN;
  float* qkv  = w + O_QKV;
  float* sc   = w + O_SC;
  float* adjw = w + O_ADJ;
  float* wr   = w + O_WR;
  float* tep  = w + O_TEP;
  float* te   = w + O_TE;
  float* xcat = w + O_XCAT;
  float* gtmp = w + O_GTMP;
  float* xg0  = w + O_XG0;
  float* xg1  = w + O_XG1;
  float* xg2  = w + O_XG2;
  ushort_t* w1tb = (ushort_t*)(w + O_W1TB);
  ushort_t* w2tb = (ushort_t*)(w + O_W2TB);
  ushort_t* awb  = (ushort_t*)(w + O_AWB);
  ushort_t* ftwb = (ushort_t*)(w + O_FTWB);
  ushort_t* smwb = (ushort_t*)(w + O_SMWB);
  ushort_t* g0wb = (ushort_t*)(w + O_G0WB);
  ushort_t* g1wb = (ushort_t*)(w + O_G1WB);
  ushort_t* g2wb = (ushort_t*)(w + O_G2WB);
  ushort_t* fcwb = (ushort_t*)(w + O_FCWB);
  int* flags = (int*)(w + O_FLAGS);

  // zero h ring slot 0 (both dirs) + chain flags + XCD queue counters
  hipMemsetAsync(hring, 0, (size_t)819200 * sizeof(ushort_t), stream);
  hipMemsetAsync(flags, 0, 512 * sizeof(int), stream);

  // ---- weight conversions (2 launches) ----
  k_cvt_plain_all<<<3072, 256, 0, stream>>>(gru_wih_f, gru_whh_f, gru_wih_b,
                                            gru_whh_b, attn_in_w, wb, awb);
  {
    TJob j0 = {seq1_w1, w1tb, 100, 256, 128, 0};       //  32 tiles
    TJob j1 = {seq1_w2, w2tb, 256, 512, 256, 32};      // 128
    TJob j2 = {fc_ta_w, ftwb, 1024, 512, 1024, 160};   // 512
    TJob j3 = {sem_w, smwb, 768, 512, 768, 672};       // 384
    TJob j4 = {gcn_w0, g0wb, 1024, 256, 1024, 1056};   // 256
    TJob j5 = {gcn_w1, g1wb, 256, 256, 256, 1312};     //  64
    TJob j6 = {gcn_w2, g2wb, 256, 256, 256, 1376};     //  64
    TJob j7 = {fc_w, fcwb, 1280, 512, 1280, 1440};     // 640 -> total 2080
    k_cvt_t_all<<<2080, 256, 0, stream>>>(j0, j1, j2, j3, j4, j5, j6, j7);
  }

  // ---- input MLP + LN (all-MFMA, fused) ----
  k_mlp_fused<<<750, 256, 0, stream>>>(x, w1tb, seq1_b1, w2tb, seq1_b2,
                                       ln2_g, ln2_b, hseqb);

  // ---- bidirectional GRU: ONE persistent launch (R10 structure + pipeline) ----
  k_gru_persist<<<256, 256, 0, stream>>>(
      hseqb, wb, gru_bih_f, gru_bhh_f, gru_bih_b, gru_bhh_b, hf32, hring, flags);

  // hn = LN(concat(hf, hb))
  k_ln_hn<<<800, 256, 0, stream>>>(hf32, hf32 + 409600, ln_g, ln_b, hn);

  // q,k projection
  k_bgemm<0><<<dim3(32, 13), 256, 0, stream>>>(
      hn, awb, attn_in_b, qkv, 800, 2048, 1024, 1024, 2048);

  // per (b,h) softmax attention
  k_scores<<<dim3(32, 8), 256, 0, stream>>>(qkv, sc);

  // semantic embedding projection + LN
  k_bgemm<0><<<dim3(8, 1), 256, 0, stream>>>(
      sem_embs, smwb, sem_b, tep, 25, 512, 768, 768, 512);
  k_ln_rows<2><<<25, 256, 0, stream>>>(tep, te, lnsem_g, lnsem_b, 512, 0);

  // fc_ta + LN3 -> Xcat[:, 0:512]
  k_bgemm<1><<<dim3(8, 13), 256, 0, stream>>>(
      hn, ftwb, fc_ta_b, wr, 800, 512, 1024, 1024, 512);
  k_ln_rows<2><<<800, 256, 0, stream>>>(wr, xcat, ln3_g, ln3_b, 1280, 0);
  k_bcast_te<<<800, 256, 0, stream>>>(te, xcat);

  // adjacency
  k_adj<<<1, 1024, 0, stream>>>(sc, te, att_alpha, dist_adj, adjw);

  // GCN layer 0
  k_bgemm<0><<<dim3(4, 13), 256, 0, stream>>>(
      xcat, g0wb, nullptr, gtmp, 800, 256, 1024, 1280, 256);
  k_mix<0, 0><<<800, 256, 0, stream>>>(adjw, gtmp, gcn_b0, nullptr, nullptr, nullptr, xg0);
  // GCN layer 1
  k_bgemm<0><<<dim3(4, 13), 256, 0, stream>>>(
      xg0, g1wb, nullptr, gtmp, 800, 256, 256, 256, 256);
  k_mix<1, 1><<<800, 256, 0, stream>>>(adjw, gtmp, gcn_b1, xg0, gln1_g, gln1_b, xg1);
  // GCN layer 2
  k_bgemm<0><<<dim3(4, 13), 256, 0, stream>>>(
      xg1, g2wb, nullptr, gtmp, 800, 256, 256, 256, 256);
  k_mix<1, 1><<<800, 256, 0, stream>>>(adjw, gtmp, gcn_b2, xg1, gln2_g, gln2_b, xg2);

  // encoder LN -> Xcat[:, 1024:1280]
  k_ln_rows<1><<<800, 256, 0, stream>>>(xg2, xcat, enc_ln_g, enc_ln_b, 1280, 1024);

  // final fc + relu -> d_out
  k_bgemm<1><<<dim3(8, 13), 256, 0, stream>>>(
      xcat, fcwb, fc_b, (float*)d_out, 800, 512, 1280, 1280, 512);
}